// Round 5
// baseline (150.554 us; speedup 1.0000x reference)
//
#include <hip/hip_runtime.h>
#include <hip/hip_bf16.h>
#include <math.h>

#define BS 8192
#define DH 1024
#define DE 256
#define NL 64

typedef __attribute__((ext_vector_type(8))) short short8;
typedef __attribute__((ext_vector_type(4))) float f32x4;
typedef unsigned short ushort;

__device__ __forceinline__ ushort bf16b(float f){
  unsigned u = __float_as_uint(f);
  unsigned r = (u + 0x7FFFu + ((u >> 16) & 1u)) >> 16;
  return (ushort)r;
}

__device__ __forceinline__ void gload_lds16(const void* g, void* l){
  __builtin_amdgcn_global_load_lds((const __attribute__((address_space(1))) void*)g,
                                   (__attribute__((address_space(3))) void*)l, 16, 0, 0);
}

// ---------------- fused prep: wcvt (b<128) | labelnorm (128<=b<192) | hist (b==192) ----------------
__global__ __launch_bounds__(256) void prep_kernel(const float* __restrict__ W, ushort* __restrict__ Wb,
    const float* __restrict__ label_emb, ushort* __restrict__ lnb,
    const int* __restrict__ labels, int* __restrict__ cnt,
    int* __restrict__ offs, int* __restrict__ groups){
  int b = blockIdx.x, t = threadIdx.x;
  if (b < 128){                        // W f32 -> bf16
    int i = (b*256 + t) * 8;
    float4 v0 = *(const float4*)(W+i);
    float4 v1 = *(const float4*)(W+i+4);
    short8 o;
    o[0]=bf16b(v0.x); o[1]=bf16b(v0.y); o[2]=bf16b(v0.z); o[3]=bf16b(v0.w);
    o[4]=bf16b(v1.x); o[5]=bf16b(v1.y); o[6]=bf16b(v1.z); o[7]=bf16b(v1.w);
    *(short8*)(Wb+i) = o;
    return;
  }
  if (b < 192){                        // label prototype normalize -> bf16
    __shared__ float red[256];
    int l = b - 128;
    float v = label_emb[l*DE + t];
    red[t] = v*v;
    __syncthreads();
    for (int s=128;s>0;s>>=1){
      if (t<s) red[t] += red[t+s];
      __syncthreads();
    }
    float inv = 1.0f / fmaxf(sqrtf(red[0]), 1e-8f);
    lnb[l*DE + t] = bf16b(v * inv);
    return;
  }
  // b == 192: histogram + stable group scatter
  __shared__ ushort loc[256][64];
  __shared__ int off_s[65];
  __shared__ int cnt_s[64];
  #pragma unroll
  for (int l=0;l<64;l++) loc[t][l]=0;
  __syncthreads();
  int base = t * 32;
  for (int i=0;i<32;i++){
    int y = labels[base+i];
    loc[t][y] = (ushort)(loc[t][y] + 1);
  }
  __syncthreads();
  if (t < 64){
    int run = 0;
    for (int tt=0;tt<256;tt++){
      int v = loc[tt][t];
      loc[tt][t] = (ushort)run;
      run += v;
    }
    cnt_s[t] = run;
    cnt[t] = run;
  }
  __syncthreads();
  if (t == 0){
    int acc = 0;
    for (int l=0;l<64;l++){ off_s[l] = acc; acc += cnt_s[l]; }
    off_s[64] = acc;
  }
  __syncthreads();
  if (t < 65) offs[t] = off_s[t];
  for (int i=0;i<32;i++){
    int idx = base + i;
    int y = labels[idx];
    int p = off_s[y] + loc[t][y];
    loc[t][y] = (ushort)(loc[t][y] + 1);
    groups[p] = idx;
  }
}

// ---------------- emb = mask @ W^T + b, row-norm; MFMA bf16, 2-phase dbuf pipeline ----------------
// BM=32, BN=256, BK=64, 16 K-steps; grid 256 (1 block/CU).
#define EMB_LOADA(KB) do { \
  va0 = *(const float4*)(aptr + (KB)); \
  va1 = *(const float4*)(aptr + (KB) + 4); \
} while(0)

#define EMB_WRITEA(P) do { \
  short8 o; \
  o[0]=bf16b(va0.x); o[1]=bf16b(va0.y); o[2]=bf16b(va0.z); o[3]=bf16b(va0.w); \
  o[4]=bf16b(va1.x); o[5]=bf16b(va1.y); o[6]=bf16b(va1.z); o[7]=bf16b(va1.w); \
  *(short8*)&Ab[P][tid*8] = o; \
} while(0)

#define EMB_STAGEB(P, KB) do { \
  _Pragma("unroll") \
  for (int q=0;q<8;q++){ \
    int chunk = q*4 + w; \
    int lin = chunk*64 + lane; \
    int row = lin >> 3, cc = lin & 7; \
    int lc = cc ^ (row & 7); \
    gload_lds16(Wb + (size_t)row*DH + (KB) + lc*8, &Bb[P][chunk*512]); \
  } \
} while(0)

#define EMB_COMPUTE(P) do { \
  _Pragma("unroll") \
  for (int kk=0;kk<2;kk++){ \
    short8 af[2], bfr[4]; \
    _Pragma("unroll") \
    for (int m=0;m<2;m++){ \
      int row = m*16 + (lane & 15); \
      int phys = (kk*4 + (lane >> 4)) ^ (row & 7); \
      af[m] = *(const short8*)&Ab[P][row*64 + phys*8]; \
    } \
    _Pragma("unroll") \
    for (int n=0;n<4;n++){ \
      int row = w*64 + n*16 + (lane & 15); \
      int phys = (kk*4 + (lane >> 4)) ^ (row & 7); \
      bfr[n] = *(const short8*)&Bb[P][row*64 + phys*8]; \
    } \
    _Pragma("unroll") \
    for (int m=0;m<2;m++) \
      _Pragma("unroll") \
      for (int n=0;n<4;n++) \
        acc[m][n] = __builtin_amdgcn_mfma_f32_16x16x32_bf16(af[m], bfr[n], acc[m][n], 0,0,0); \
  } \
} while(0)

__global__ __launch_bounds__(256) void emb_kernel(const float* __restrict__ mask,
    const ushort* __restrict__ Wb, const float* __restrict__ bias,
    ushort* __restrict__ enb){
  __shared__ ushort Ab[2][32*64];    // 2 x 4KB
  __shared__ ushort Bb[2][256*64];   // 2 x 32KB
  __shared__ float sq[4][32];
  __shared__ float inv_s[32];
  int tid = threadIdx.x, lane = tid & 63, w = tid >> 6;
  int rb = blockIdx.x * 32;
  int arow = tid >> 3, alc = (tid & 7) ^ (arow & 7);
  const float* aptr = mask + (size_t)(rb + arow)*DH + alc*8;
  float4 va0, va1;
  f32x4 acc[2][4] = {};
  // prologue: stage step 0
  EMB_LOADA(0);
  EMB_WRITEA(0);
  EMB_STAGEB(0, 0);
  __syncthreads();
  int buf = 0;
  for (int kb = 0; kb < 16; kb++){
    if (kb < 15){
      EMB_LOADA((kb+1)*64);
      EMB_STAGEB(buf^1, (kb+1)*64);
    }
    EMB_COMPUTE(buf);
    if (kb < 15) EMB_WRITEA(buf^1);
    __syncthreads();
    buf ^= 1;
  }
  // epilogue: +bias, row sumsq, normalize, write bf16
  int qr = lane >> 4, c15 = lane & 15;
  float bv[4];
  #pragma unroll
  for (int n=0;n<4;n++) bv[n] = bias[w*64 + n*16 + c15];
  #pragma unroll
  for (int m=0;m<2;m++){
    #pragma unroll
    for (int r=0;r<4;r++){
      float s = 0.f;
      #pragma unroll
      for (int n=0;n<4;n++){
        float v = acc[m][n][r] + bv[n];
        acc[m][n][r] = v;
        s += v*v;
      }
      #pragma unroll
      for (int msk=8; msk>=1; msk>>=1) s += __shfl_xor(s, msk);
      if (c15 == 0) sq[w][m*16 + qr*4 + r] = s;
    }
  }
  __syncthreads();
  if (tid < 32){
    float s = sq[0][tid] + sq[1][tid] + sq[2][tid] + sq[3][tid];
    inv_s[tid] = 1.0f / fmaxf(sqrtf(s), 1e-8f);
  }
  __syncthreads();
  #pragma unroll
  for (int m=0;m<2;m++){
    #pragma unroll
    for (int r=0;r<4;r++){
      int row = m*16 + qr*4 + r;
      float iv = inv_s[row];
      #pragma unroll
      for (int n=0;n<4;n++){
        int col = w*64 + n*16 + c15;
        enb[(size_t)(rb+row)*DE + col] = bf16b(acc[m][n][r] * iv);
      }
    }
  }
}

// ---------------- N pass: symmetric upper triangle, compact 1D grid, 2-phase dbuf ----------------
#define NPASS_STAGE(P, KB) do { \
  _Pragma("unroll") \
  for (int q=0;q<4;q++){ \
    int chunk = q*4 + w; \
    int lin = chunk*64 + lane; \
    int row = lin >> 3, cc = lin & 7; \
    int lc = cc ^ (row & 7); \
    gload_lds16(enb + (size_t)(rb + row)*DE + (KB) + lc*8, &Ab[P][chunk*512]); \
    gload_lds16(enb + (size_t)(cb + row)*DE + (KB) + lc*8, &Bb[P][chunk*512]); \
  } \
} while(0)

#define NPASS_COMPUTE(P) do { \
  _Pragma("unroll") \
  for (int kk=0;kk<2;kk++){ \
    short8 af[4], bfr[4]; \
    _Pragma("unroll") \
    for (int m=0;m<4;m++){ \
      int row = wr*64 + m*16 + (lane & 15); \
      int phys = (kk*4 + (lane >> 4)) ^ (row & 7); \
      af[m] = *(const short8*)&Ab[P][row*64 + phys*8]; \
    } \
    _Pragma("unroll") \
    for (int n=0;n<4;n++){ \
      int row = wc*64 + n*16 + (lane & 15); \
      int phys = (kk*4 + (lane >> 4)) ^ (row & 7); \
      bfr[n] = *(const short8*)&Bb[P][row*64 + phys*8]; \
    } \
    _Pragma("unroll") \
    for (int m=0;m<4;m++) \
      _Pragma("unroll") \
      for (int n=0;n<4;n++) \
        acc[m][n] = __builtin_amdgcn_mfma_f32_16x16x32_bf16(af[m], bfr[n], acc[m][n], 0,0,0); \
  } \
} while(0)

__global__ __launch_bounds__(256) void npass_kernel(const ushort* __restrict__ enb,
    const int* __restrict__ labels, float* __restrict__ N_part){
  // decode linear block id -> (bi, bj), bi <= bj
  int tlin = blockIdx.x;
  int i = (int)((sqrtf(8.0f*tlin + 1.0f) - 1.0f) * 0.5f);
  while ((i+1)*(i+2)/2 <= tlin) i++;
  while (i*(i+1)/2 > tlin) i--;
  int bj = i, bi = tlin - i*(i+1)/2;
  __shared__ ushort Ab[2][128*64];   // 2 x 16KB
  __shared__ ushort Bb[2][128*64];   // 2 x 16KB
  __shared__ float nredA[2][128];
  __shared__ float nredB[2][128];
  int tid = threadIdx.x, lane = tid & 63, w = tid >> 6;
  int wr = w >> 1, wc = w & 1;
  int rb = bi * 128;
  int cb = bj * 128;
  f32x4 acc[4][4] = {};
  // prologue
  NPASS_STAGE(0, 0);
  __syncthreads();
  int buf = 0;
  #pragma unroll
  for (int kb = 0; kb < 4; kb++){
    if (kb < 3) NPASS_STAGE(buf^1, (kb+1)*64);
    NPASS_COMPUTE(buf);
    __syncthreads();
    buf ^= 1;
  }
  // epilogue: mask + exp; row-reduce (rows of bi) AND col-reduce (rows of bj)
  int qr = lane >> 4, c15 = lane & 15;
  int cl[4];
  #pragma unroll
  for (int n=0;n<4;n++) cl[n] = labels[cb + wc*64 + n*16 + c15];
  float scol[4] = {0.f,0.f,0.f,0.f};
  #pragma unroll
  for (int m=0;m<4;m++){
    #pragma unroll
    for (int r=0;r<4;r++){
      int rlab = labels[rb + wr*64 + m*16 + qr*4 + r];
      float srow = 0.f;
      #pragma unroll
      for (int n=0;n<4;n++){
        float e = __expf(acc[m][n][r]);
        e = (cl[n] != rlab) ? e : 0.f;
        srow += e;
        scol[n] += e;
      }
      #pragma unroll
      for (int msk=8; msk>=1; msk>>=1) srow += __shfl_xor(srow, msk);
      if (c15 == 0) nredA[wc][wr*64 + m*16 + qr*4 + r] = srow;
    }
  }
  #pragma unroll
  for (int n=0;n<4;n++){
    scol[n] += __shfl_xor(scol[n], 16);
    scol[n] += __shfl_xor(scol[n], 32);
  }
  if (qr == 0){
    #pragma unroll
    for (int n=0;n<4;n++) nredB[wr][wc*64 + n*16 + c15] = scol[n];
  }
  __syncthreads();
  if (tid < 128){
    N_part[(size_t)bj*BS + rb + tid] = nredA[0][tid] + nredA[1][tid];
    if (bi != bj)
      N_part[(size_t)bi*BS + cb + tid] = nredB[0][tid] + nredB[1][tid];
  }
}

// ---------------- fused C-pass: pos, rowsum, T/G column partials (MFMA) ----------------
__global__ __launch_bounds__(256) void c2_kernel(const ushort* __restrict__ enb,
    const ushort* __restrict__ lnb, const int* __restrict__ labels,
    float* __restrict__ pos, float* __restrict__ rowsum,
    float* __restrict__ T_part, float* __restrict__ G_part){
  __shared__ ushort Ab[64*64];
  __shared__ ushort Bb[64*64];
  __shared__ float TpS[4][64];
  __shared__ float GpS[4][64];
  int tid = threadIdx.x, lane = tid & 63, w = tid >> 6;
  int qr = lane >> 4, c15 = lane & 15;
  int rb = blockIdx.x * 64;
  f32x4 acc[4] = {};
  for (int kb = 0; kb < DE; kb += 64){
    #pragma unroll
    for (int q=0;q<2;q++){
      int chunk = q*4 + w;
      int lin = chunk*64 + lane;
      int row = lin >> 3, cc = lin & 7;
      int lc = cc ^ (row & 7);
      gload_lds16(enb + (size_t)(rb+row)*DE + kb + lc*8, &Ab[(size_t)chunk*64*8]);
    }
    #pragma unroll
    for (int q=0;q<2;q++){
      int chunk = q*4 + w;
      int lin = chunk*64 + lane;
      int row = lin >> 3, cc = lin & 7;
      int lc = cc ^ (row & 7);
      gload_lds16(lnb + (size_t)row*DE + kb + lc*8, &Bb[(size_t)chunk*64*8]);
    }
    __syncthreads();
    #pragma unroll
    for (int kk=0;kk<2;kk++){
      int arow = w*16 + (lane & 15);
      int aphys = (kk*4 + (lane >> 4)) ^ (arow & 7);
      short8 af = *(const short8*)&Ab[arow*64 + aphys*8];
      #pragma unroll
      for (int ni=0;ni<4;ni++){
        int brow = ni*16 + (lane & 15);
        int bphys = (kk*4 + (lane >> 4)) ^ (brow & 7);
        short8 bfr = *(const short8*)&Bb[brow*64 + bphys*8];
        acc[ni] = __builtin_amdgcn_mfma_f32_16x16x32_bf16(af, bfr, acc[ni], 0,0,0);
      }
    }
    __syncthreads();
  }
  int yr[4];
  #pragma unroll
  for (int r=0;r<4;r++) yr[r] = labels[rb + w*16 + qr*4 + r];
  float e[4][4];
  #pragma unroll
  for (int ni=0;ni<4;ni++)
    #pragma unroll
    for (int r=0;r<4;r++) e[ni][r] = __expf(acc[ni][r]);
  #pragma unroll
  for (int r=0;r<4;r++){
    float rs = e[0][r]+e[1][r]+e[2][r]+e[3][r];
    float ps = 0.f;
    #pragma unroll
    for (int ni=0;ni<4;ni++) if (ni*16 + c15 == yr[r]) ps = acc[ni][r];
    #pragma unroll
    for (int msk=8; msk>=1; msk>>=1){ rs += __shfl_xor(rs, msk); ps += __shfl_xor(ps, msk); }
    if (c15 == 0){
      int grow = rb + w*16 + qr*4 + r;
      rowsum[grow] = rs;
      pos[grow] = ps;
    }
  }
  #pragma unroll
  for (int ni=0;ni<4;ni++){
    int col = ni*16 + c15;
    float t = 0.f, g = 0.f;
    #pragma unroll
    for (int r=0;r<4;r++){
      t += e[ni][r];
      if (col == yr[r]) g += e[ni][r];
    }
    t += __shfl_xor(t, 16); t += __shfl_xor(t, 32);
    g += __shfl_xor(g, 16); g += __shfl_xor(g, 32);
    if (qr == 0){ TpS[w][col] = t; GpS[w][col] = g; }
  }
  __syncthreads();
  if (tid < 64){
    T_part[(size_t)blockIdx.x*64 + tid] = TpS[0][tid]+TpS[1][tid]+TpS[2][tid]+TpS[3][tid];
    G_part[(size_t)blockIdx.x*64 + tid] = GpS[0][tid]+GpS[1][tid]+GpS[2][tid]+GpS[3][tid];
  }
}

__global__ void reduceN_kernel(const float* __restrict__ N_part, float* __restrict__ Nrow){
  int i = blockIdx.x*256 + threadIdx.x;
  float s = 0.f;
  #pragma unroll
  for (int c=0;c<64;c++) s += N_part[(size_t)c*BS + i];
  Nrow[i] = s;
}

// ---------------- same-label pairs via gathered MFMA group-GEMM ----------------
__global__ __launch_bounds__(256) void pairs_kernel(const ushort* __restrict__ enb,
    const int* __restrict__ cnt, const int* __restrict__ offs,
    const int* __restrict__ groups, const float* __restrict__ Nrow,
    float* __restrict__ pairp){
  __shared__ ushort Ab[64*64];
  __shared__ ushort Bb[256*64];
  __shared__ int aidx[64];
  __shared__ int gidx[256];
  __shared__ float red[256];
  int l = blockIdx.x, rt = blockIdx.y;
  int m = cnt[l], off = offs[l];
  int tid = threadIdx.x, lane = tid & 63, w = tid >> 6;
  int qr = lane >> 4, c15 = lane & 15;
  float sum = 0.f;
  for (int ra = rt*64; ra < m; ra += 256){
    __syncthreads();
    if (tid < 64){ int a = ra + tid; aidx[tid] = groups[off + (a < m ? a : 0)]; }
    for (int cb2 = 0; cb2 < m; cb2 += 256){
      __syncthreads();
      { int b = cb2 + tid; gidx[tid] = groups[off + (b < m ? b : 0)]; }
      __syncthreads();
      f32x4 acc[4][4] = {};
      for (int kb = 0; kb < DE; kb += 64){
        #pragma unroll
        for (int q=0;q<2;q++){
          int chunk = q*4 + w;
          int lin = chunk*64 + lane;
          int row = lin >> 3, cc = lin & 7;
          int lc = cc ^ (row & 7);
          gload_lds16(enb + (size_t)aidx[row]*DE + kb + lc*8, &Ab[(size_t)chunk*64*8]);
        }
        #pragma unroll
        for (int q=0;q<8;q++){
          int chunk = q*4 + w;
          int lin = chunk*64 + lane;
          int row = lin >> 3, cc = lin & 7;
          int lc = cc ^ (row & 7);
          gload_lds16(enb + (size_t)gidx[row]*DE + kb + lc*8, &Bb[(size_t)chunk*64*8]);
        }
        __syncthreads();
        #pragma unroll
        for (int kk=0;kk<2;kk++){
          short8 af[4], bfr[4];
          #pragma unroll
          for (int mi=0;mi<4;mi++){
            int row = mi*16 + (lane & 15);
            int phys = (kk*4 + (lane >> 4)) ^ (row & 7);
            af[mi] = *(const short8*)&Ab[row*64 + phys*8];
          }
          #pragma unroll
          for (int ni=0;ni<4;ni++){
            int row = w*64 + ni*16 + (lane & 15);
            int phys = (kk*4 + (lane >> 4)) ^ (row & 7);
            bfr[ni] = *(const short8*)&Bb[row*64 + phys*8];
          }
          #pragma unroll
          for (int mi=0;mi<4;mi++)
            #pragma unroll
            for (int ni=0;ni<4;ni++)
              acc[mi][ni] = __builtin_amdgcn_mfma_f32_16x16x32_bf16(af[mi], bfr[ni], acc[mi][ni], 0,0,0);
        }
        __syncthreads();
      }
      #pragma unroll
      for (int mi=0;mi<4;mi++){
        #pragma unroll
        for (int r=0;r<4;r++){
          int arel = mi*16 + qr*4 + r;
          int a = ra + arel;
          if (a < m){
            float Ni = Nrow[aidx[arel]];
            #pragma unroll
            for (int ni=0;ni<4;ni++){
              int b = cb2 + w*64 + ni*16 + c15;
              if (b < m && b != a){
                float s = acc[mi][ni][r];
                sum += -s + __logf(Ni + __expf(s));
              }
            }
          }
        }
      }
    }
  }
  red[tid] = sum;
  __syncthreads();
  for (int s=128;s>0;s>>=1){ if (tid<s) red[tid]+=red[tid+s]; __syncthreads(); }
  if (tid==0) pairp[l*4 + rt] = red[0];
}

// ---------------- final scalar assembly (f32 math, f64 accumulation) ----------------
__global__ void finalize_kernel(const int* __restrict__ labels, const int* __restrict__ cnt,
    const float* __restrict__ Nrow, const float* __restrict__ pos,
    const float* __restrict__ rowsum, const float* __restrict__ T_part,
    const float* __restrict__ G_part, const float* __restrict__ pairp,
    float* __restrict__ out){
  __shared__ double red[3*256];
  __shared__ float TGp[4][64];
  __shared__ float TGf[64];
  int t = threadIdx.x;
  {
    int l = t & 63, qq = t >> 6;
    float ts = 0.f, gs = 0.f;
    for (int b=qq; b<128; b+=4){ ts += T_part[b*64 + l]; gs += G_part[b*64 + l]; }
    TGp[qq][l] = ts - gs;
  }
  __syncthreads();
  if (t < 64) TGf[t] = TGp[0][t]+TGp[1][t]+TGp[2][t]+TGp[3][t];
  __syncthreads();
  double a=0.0, p1=0.0, p2=0.0;
  for (int i=t; i<BS; i+=256){
    int y = labels[i];
    float Ni = Nrow[i];
    a += (double)((float)(BS - cnt[y]) * __logf(Ni + 1.0f));
    float ps = pos[i];
    p1 += (double)(-ps + __logf(rowsum[i]));
    p2 += (double)(-ps + __logf(TGf[y] + __expf(ps)));
  }
  red[t]=a; red[256+t]=p1; red[512+t]=p2;
  __syncthreads();
  for (int s=128;s>0;s>>=1){
    if (t<s){ red[t]+=red[t+s]; red[256+t]+=red[256+t+s]; red[512+t]+=red[512+t+s]; }
    __syncthreads();
  }
  if (t==0){
    double pair = 0.0;
    for (int l=0;l<256;l++) pair += (double)pairp[l];
    double inter = (red[0] + pair) / ((double)BS * (double)BS);
    double proto = (red[256] + red[512]) / (double)BS;
    out[0] = (float)(0.5*inter + 0.5*proto);
  }
}

extern "C" void kernel_launch(void* const* d_in, const int* in_sizes, int n_in,
                              void* d_out, int out_size, void* d_ws, size_t ws_size,
                              hipStream_t stream){
  const float* mask  = (const float*)d_in[0];
  const float* W     = (const float*)d_in[1];
  const float* bias  = (const float*)d_in[2];
  const float* lemb  = (const float*)d_in[3];
  const int*   labels= (const int*)d_in[4];
  float* out = (float*)d_out;

  // workspace layout (~7 MB)
  ushort* enb    = (ushort*)d_ws;                   // 8192*256 bf16 (4MB)
  ushort* Wb     = enb + (size_t)BS*DE;             // 256*1024 bf16 (512KB)
  ushort* lnb    = Wb + (size_t)DE*DH;              // 64*256 bf16 (32KB)
  float*  N_part = (float*)(lnb + (size_t)NL*DE);   // 64*8192 (2MB)
  float*  Nrow   = N_part + (size_t)64*BS;          // 8192
  float*  pos    = Nrow + BS;                       // 8192
  float*  rowsum = pos + BS;                        // 8192
  float*  T_part = rowsum + BS;                     // 128*64
  float*  G_part = T_part + 128*64;                 // 128*64
  float*  pairp  = G_part + 128*64;                 // 256
  int* cnt    = (int*)(pairp + 256);                // 64
  int* offs   = cnt + NL;                           // 65 (pad 68)
  int* groups = offs + 68;                          // 8192

  hipLaunchKernelGGL(prep_kernel,     dim3(193), dim3(256), 0, stream, W, Wb, lemb, lnb, labels, cnt, offs, groups);
  hipLaunchKernelGGL(emb_kernel,      dim3(BS/32), dim3(256), 0, stream, mask, Wb, bias, enb);
  hipLaunchKernelGGL(npass_kernel,    dim3(64*65/2), dim3(256), 0, stream, enb, labels, N_part);
  hipLaunchKernelGGL(c2_kernel,       dim3(BS/64), dim3(256), 0, stream, enb, lnb, labels, pos, rowsum, T_part, G_part);
  hipLaunchKernelGGL(reduceN_kernel,  dim3(BS/256), dim3(256), 0, stream, N_part, Nrow);
  hipLaunchKernelGGL(pairs_kernel,    dim3(NL, 4), dim3(256), 0, stream, enb, cnt, offs, groups, Nrow, pairp);
  hipLaunchKernelGGL(finalize_kernel, dim3(1), dim3(256), 0, stream, labels, cnt, Nrow, pos, rowsum, T_part, G_part, pairp, out);
}